// Round 1
// baseline (1336.533 us; speedup 1.0000x reference)
//
#include <hip/hip_runtime.h>
#include <cfloat>

#define BB 64
#define NN 16384
#define CC 128
#define KK 24
#define OUTW (3 + 2*CC)   // 259
#define STRIDE 51         // 24 sum + 24 max + 3 pad; odd stride -> conflict-free banks

// ---------------- k1: labels pack + counts + xyz sums (one block per batch) ---------
__global__ __launch_bounds__(256) void k1_labels_xyz(
    const float* __restrict__ xyz, const int* __restrict__ labels,
    unsigned char* __restrict__ lab8, float* __restrict__ cnt, float* __restrict__ sxyz)
{
    __shared__ float bins[4][KK][4];   // [wave][k][count,x,y,z]
    const int tid = threadIdx.x;
    const int b = blockIdx.x;
    const int w = tid >> 6;

    for (int i = tid; i < 4*KK*4; i += 256) ((float*)bins)[i] = 0.f;
    __syncthreads();

    const int4*   lrow = (const int4*)(labels + (size_t)b*NN);
    const float4* xrow = (const float4*)(xyz + (size_t)b*NN*3);
    unsigned int* orow = (unsigned int*)(lab8 + (size_t)b*NN);

    for (int it = 0; it < NN/(256*4); ++it) {       // 16 iterations
        int n4 = it*256 + tid;
        int4 l = lrow[n4];
        orow[n4] = (unsigned)l.x | ((unsigned)l.y<<8) | ((unsigned)l.z<<16) | ((unsigned)l.w<<24);
        float4 f0 = xrow[n4*3+0], f1 = xrow[n4*3+1], f2 = xrow[n4*3+2];
        float px[4] = {f0.x, f0.w, f1.z, f2.y};
        float py[4] = {f0.y, f1.x, f1.w, f2.z};
        float pz[4] = {f0.z, f1.y, f2.x, f2.w};
        int   ls[4] = {l.x, l.y, l.z, l.w};
        #pragma unroll
        for (int j = 0; j < 4; ++j) {
            float* bb = bins[w][ls[j]];
            atomicAdd(&bb[0], 1.0f);
            atomicAdd(&bb[1], px[j]);
            atomicAdd(&bb[2], py[j]);
            atomicAdd(&bb[3], pz[j]);
        }
    }
    __syncthreads();
    if (tid < KK*4) {
        int k = tid >> 2, j = tid & 3;
        float v = bins[0][k][j] + bins[1][k][j] + bins[2][k][j] + bins[3][k][j];
        if (j == 0) cnt[b*KK + k] = v;
        else        sxyz[(b*KK + k)*3 + (j-1)] = v;
    }
}

// ---------------- k2: per-(b,c)-row segment sum+max of features --------------------
// One wave per row (b,c); per-thread private bins in LDS.
__global__ __launch_bounds__(256) void k2_feat(
    const float* __restrict__ features, const unsigned char* __restrict__ lab8,
    float* __restrict__ sumf, float* __restrict__ maxf)
{
    __shared__ float bins[256*STRIDE];   // 52224 B
    const int tid  = threadIdx.x;
    const int lane = tid & 63;
    const int w    = tid >> 6;
    const int row  = blockIdx.x*4 + w;   // row = b*CC + c
    const int b    = row >> 7;           // /128
    const int c    = row & 127;

    float* my = bins + tid*STRIDE;       // [0..23]=sum, [24..47]=max
    #pragma unroll
    for (int k = 0; k < KK; ++k) { my[k] = 0.f; my[24+k] = -FLT_MAX; }

    const float4* frow = (const float4*)(features + (size_t)row * NN);
    const uchar4* lrow = (const uchar4*)(lab8 + (size_t)b * NN);

    for (int it = 0; it < NN/4/64; ++it) {   // 64 iterations
        int idx = it*64 + lane;
        float4 v = frow[idx];
        uchar4 l = lrow[idx];
        { float* p = my + l.x; atomicAdd(p, v.x); float* q = p + 24; *q = fmaxf(*q, v.x); }
        { float* p = my + l.y; atomicAdd(p, v.y); float* q = p + 24; *q = fmaxf(*q, v.y); }
        { float* p = my + l.z; atomicAdd(p, v.z); float* q = p + 24; *q = fmaxf(*q, v.z); }
        { float* p = my + l.w; atomicAdd(p, v.w); float* q = p + 24; *q = fmaxf(*q, v.w); }
    }
    __syncthreads();

    if (lane < KK) {
        const int wbase = (tid & ~63) * STRIDE;
        float s = 0.f, m = -FLT_MAX;
        for (int t = 0; t < 64; ++t) {
            const float* p = bins + wbase + t*STRIDE;
            s += p[lane];
            m  = fmaxf(m, p[24 + lane]);
        }
        size_t o = ((size_t)b*KK + lane)*CC + c;
        sumf[o] = s;
        maxf[o] = m;
    }
}

// ---------------- k3: epilogue -----------------------------------------------------
__global__ __launch_bounds__(128) void k3_final(
    const float* __restrict__ cnt, const float* __restrict__ sxyz,
    const float* __restrict__ sumf, const float* __restrict__ maxf,
    float* __restrict__ out)
{
    const int bk = blockIdx.x;       // b*KK + k
    const int c  = threadIdx.x;      // 0..127
    float cn = cnt[bk];
    float inv = 1.0f / fmaxf(cn, 1.0f);
    float* orow = out + (size_t)bk * OUTW;
    if (c < 3) orow[c] = sxyz[bk*3 + c] * inv;
    float s    = sumf[(size_t)bk*CC + c];
    float mean = s * inv;
    orow[3 + c] = mean;
    float m    = maxf[(size_t)bk*CC + c];
    orow[3 + CC + c] = (cn > 0.f) ? fmaxf(m - mean, 0.f) : 0.f;
}

extern "C" void kernel_launch(void* const* d_in, const int* in_sizes, int n_in,
                              void* d_out, int out_size, void* d_ws, size_t ws_size,
                              hipStream_t stream) {
    const float* xyz      = (const float*)d_in[0];
    const float* features = (const float*)d_in[1];
    const int*   labels   = (const int*)d_in[2];
    float* out = (float*)d_out;

    char* ws = (char*)d_ws;
    const size_t SZ_SUMF = (size_t)BB*KK*CC*4;   // 786432
    const size_t SZ_SXYZ = (size_t)BB*KK*3*4;    // 18432
    const size_t SZ_CNT  = (size_t)BB*KK*4;      // 6144
    float* sumf = (float*)ws;
    float* maxf = (float*)(ws + SZ_SUMF);
    float* sxyz = (float*)(ws + 2*SZ_SUMF);
    float* cnt  = (float*)(ws + 2*SZ_SUMF + SZ_SXYZ);
    unsigned char* lab8 = (unsigned char*)(ws + 2*SZ_SUMF + SZ_SXYZ + SZ_CNT);

    k1_labels_xyz<<<BB, 256, 0, stream>>>(xyz, labels, lab8, cnt, sxyz);
    k2_feat<<<BB*CC/4, 256, 0, stream>>>(features, lab8, sumf, maxf);
    k3_final<<<BB*KK, 128, 0, stream>>>(cnt, sxyz, sumf, maxf, out);
}

// Round 2
// 1255.103 us; speedup vs baseline: 1.0649x; 1.0649x over previous
//
#include <hip/hip_runtime.h>
#include <cfloat>

#define BB 64
#define NN 16384
#define CC 128
#define KK 24
#define OUTW (3 + 2*CC)   // 259
#define STRIDE 49         // 24 sum + 24 max + 1 pad; odd stride -> bank spread

__device__ __forceinline__ unsigned fenc(float v) {
    unsigned b = __float_as_uint(v);
    return b ^ ((unsigned)((int)b >> 31) | 0x80000000u);
}
__device__ __forceinline__ float fdec(unsigned u) {
    unsigned b = (u & 0x80000000u) ? (u ^ 0x80000000u) : ~u;
    return __uint_as_float(b);
}

// ---------------- k0: zero global accumulators -------------------------------------
__global__ __launch_bounds__(256) void k0_init(float* __restrict__ cnt, float* __restrict__ sxyz)
{
    int i = blockIdx.x*256 + threadIdx.x;
    if (i < BB*KK) cnt[i] = 0.f;
    if (i < BB*KK*3) sxyz[i] = 0.f;
}

// ---------------- k1: labels pack + counts + xyz sums (16 blocks per batch) --------
__global__ __launch_bounds__(256) void k1_labels_xyz(
    const float* __restrict__ xyz, const int* __restrict__ labels,
    unsigned char* __restrict__ lab8, float* __restrict__ cnt, float* __restrict__ sxyz)
{
    __shared__ float bins[4][KK][4];   // [wave][k][count,x,y,z]
    const int tid   = threadIdx.x;
    const int b     = blockIdx.x >> 4;
    const int chunk = blockIdx.x & 15;
    const int w     = tid >> 6;

    for (int i = tid; i < 4*KK*4; i += 256) ((float*)bins)[i] = 0.f;
    __syncthreads();

    const int4*   lrow = (const int4*)(labels + (size_t)b*NN);
    const float4* xrow = (const float4*)(xyz + (size_t)b*NN*3);
    unsigned int* orow = (unsigned int*)(lab8 + (size_t)b*NN);

    int n4 = chunk*256 + tid;            // int4 index within batch, [0,4096)
    int4 l = lrow[n4];
    orow[n4] = (unsigned)l.x | ((unsigned)l.y<<8) | ((unsigned)l.z<<16) | ((unsigned)l.w<<24);
    float4 f0 = xrow[n4*3+0], f1 = xrow[n4*3+1], f2 = xrow[n4*3+2];
    float px[4] = {f0.x, f0.w, f1.z, f2.y};
    float py[4] = {f0.y, f1.x, f1.w, f2.z};
    float pz[4] = {f0.z, f1.y, f2.x, f2.w};
    int   ls[4] = {l.x, l.y, l.z, l.w};
    #pragma unroll
    for (int j = 0; j < 4; ++j) {
        float* bb = bins[w][ls[j]];
        atomicAdd(&bb[0], 1.0f);   // no-return ds_add_f32
        atomicAdd(&bb[1], px[j]);
        atomicAdd(&bb[2], py[j]);
        atomicAdd(&bb[3], pz[j]);
    }
    __syncthreads();
    if (tid < KK*4) {
        int k = tid >> 2, j = tid & 3;
        float v = bins[0][k][j] + bins[1][k][j] + bins[2][k][j] + bins[3][k][j];
        if (j == 0) atomicAdd(&cnt[b*KK + k], v);
        else        atomicAdd(&sxyz[(b*KK + k)*3 + (j-1)], v);
    }
}

// ---------------- k2: per-(b,c)-row segment sum+max of features --------------------
// One wave per row (b,c); per-thread private bins in LDS; ALL per-element LDS ops
// are no-return atomics (ds_add_f32 / ds_max_u32) -> fire-and-forget, no dep chain.
__global__ __launch_bounds__(256) void k2_feat(
    const float* __restrict__ features, const unsigned char* __restrict__ lab8,
    float* __restrict__ sumf, unsigned* __restrict__ maxf)
{
    __shared__ float bins[256*STRIDE];   // 50176 B -> 3 blocks/CU
    const int tid  = threadIdx.x;
    const int lane = tid & 63;
    const int row  = blockIdx.x*4 + (tid >> 6);   // row = b*CC + c
    const int b    = row >> 7;
    const int c    = row & 127;

    float*    mys = bins + tid*STRIDE;            // [0..23]  sums
    unsigned* mym = (unsigned*)(mys + KK);        // [24..47] max codes
    #pragma unroll
    for (int k = 0; k < KK; ++k) { mys[k] = 0.f; mym[k] = 0u; }

    const float4* frow = (const float4*)(features + (size_t)row * NN);
    const uchar4* lrow = (const uchar4*)(lab8 + (size_t)b * NN);

    for (int it = 0; it < NN/4/64; ++it) {   // 64 iterations
        int idx = it*64 + lane;
        float4 v = frow[idx];
        uchar4 l = lrow[idx];
        atomicAdd(&mys[l.x], v.x);  atomicMax(&mym[l.x], fenc(v.x));
        atomicAdd(&mys[l.y], v.y);  atomicMax(&mym[l.y], fenc(v.y));
        atomicAdd(&mys[l.z], v.z);  atomicMax(&mym[l.z], fenc(v.z));
        atomicAdd(&mys[l.w], v.w);  atomicMax(&mym[l.w], fenc(v.w));
    }
    __syncthreads();

    if (lane < KK) {
        const int wbase = (tid & ~63) * STRIDE;
        float s = 0.f; unsigned m = 0u;
        for (int t = 0; t < 64; ++t) {
            const float*    p = bins + wbase + t*STRIDE;
            const unsigned* q = (const unsigned*)(p + KK);
            s += p[lane];
            m  = max(m, q[lane]);
        }
        size_t o = ((size_t)b*KK + lane)*CC + c;
        sumf[o] = s;
        maxf[o] = m;
    }
}

// ---------------- k3: epilogue -----------------------------------------------------
__global__ __launch_bounds__(128) void k3_final(
    const float* __restrict__ cnt, const float* __restrict__ sxyz,
    const float* __restrict__ sumf, const unsigned* __restrict__ maxf,
    float* __restrict__ out)
{
    const int bk = blockIdx.x;       // b*KK + k
    const int c  = threadIdx.x;      // 0..127
    float cn = cnt[bk];
    float inv = 1.0f / fmaxf(cn, 1.0f);
    float* orow = out + (size_t)bk * OUTW;
    if (c < 3) orow[c] = sxyz[bk*3 + c] * inv;
    float s    = sumf[(size_t)bk*CC + c];
    float mean = s * inv;
    orow[3 + c] = mean;
    float m    = fdec(maxf[(size_t)bk*CC + c]);
    orow[3 + CC + c] = (cn > 0.f) ? fmaxf(m - mean, 0.f) : 0.f;
}

extern "C" void kernel_launch(void* const* d_in, const int* in_sizes, int n_in,
                              void* d_out, int out_size, void* d_ws, size_t ws_size,
                              hipStream_t stream) {
    const float* xyz      = (const float*)d_in[0];
    const float* features = (const float*)d_in[1];
    const int*   labels   = (const int*)d_in[2];
    float* out = (float*)d_out;

    char* ws = (char*)d_ws;
    const size_t SZ_SUMF = (size_t)BB*KK*CC*4;   // 786432
    const size_t SZ_SXYZ = (size_t)BB*KK*3*4;    // 18432
    const size_t SZ_CNT  = (size_t)BB*KK*4;      // 6144
    float*    sumf = (float*)ws;
    unsigned* maxf = (unsigned*)(ws + SZ_SUMF);
    float*    sxyz = (float*)(ws + 2*SZ_SUMF);
    float*    cnt  = (float*)(ws + 2*SZ_SUMF + SZ_SXYZ);
    unsigned char* lab8 = (unsigned char*)(ws + 2*SZ_SUMF + SZ_SXYZ + SZ_CNT);

    k0_init<<<(BB*KK*3 + 255)/256, 256, 0, stream>>>(cnt, sxyz);
    k1_labels_xyz<<<BB*16, 256, 0, stream>>>(xyz, labels, lab8, cnt, sxyz);
    k2_feat<<<BB*CC/4, 256, 0, stream>>>(features, lab8, sumf, maxf);
    k3_final<<<BB*KK, 128, 0, stream>>>(cnt, sxyz, sumf, maxf, out);
}

// Round 3
// 962.272 us; speedup vs baseline: 1.3889x; 1.3043x over previous
//
#include <hip/hip_runtime.h>

#define BB 64
#define NN 16384
#define CC 128
#define KK 24
#define OUTW (3 + 2*CC)   // 259
#define NCHUNK 16

// ---------------- k1: counts + xyz sums, per-chunk partials (no global atomics) ----
__global__ __launch_bounds__(256) void k1_cnt_xyz(
    const float* __restrict__ xyz, const int* __restrict__ labels,
    float* __restrict__ pcnt, float* __restrict__ psxyz)
{
    __shared__ float bins[4][KK][4];   // [wave][k][count,x,y,z]
    const int tid   = threadIdx.x;
    const int b     = blockIdx.x >> 4;
    const int chunk = blockIdx.x & 15;
    const int w     = tid >> 6;

    for (int i = tid; i < 4*KK*4; i += 256) ((float*)bins)[i] = 0.f;
    __syncthreads();

    const int4*   lrow = (const int4*)(labels + (size_t)b*NN);
    const float4* xrow = (const float4*)(xyz + (size_t)b*NN*3);

    int n4 = chunk*256 + tid;            // int4 index within batch, [0,4096)
    int4 l = lrow[n4];
    float4 f0 = xrow[n4*3+0], f1 = xrow[n4*3+1], f2 = xrow[n4*3+2];
    float px[4] = {f0.x, f0.w, f1.z, f2.y};
    float py[4] = {f0.y, f1.x, f1.w, f2.z};
    float pz[4] = {f0.z, f1.y, f2.x, f2.w};
    int   ls[4] = {l.x, l.y, l.z, l.w};
    #pragma unroll
    for (int j = 0; j < 4; ++j) {
        float* bb = bins[w][ls[j]];
        atomicAdd(&bb[0], 1.0f);
        atomicAdd(&bb[1], px[j]);
        atomicAdd(&bb[2], py[j]);
        atomicAdd(&bb[3], pz[j]);
    }
    __syncthreads();
    if (tid < KK*4) {
        int k = tid >> 2, j = tid & 3;
        float v = bins[0][k][j] + bins[1][k][j] + bins[2][k][j] + bins[3][k][j];
        int base = (b*NCHUNK + chunk)*KK + k;
        if (j == 0) pcnt[base] = v;
        else        psxyz[base*3 + (j-1)] = v;
    }
}

// ---------------- k2: VALU select-accumulate, zero LDS, zero atomics ----------------
// One wave per channel-PAIR (c, c+64) of one batch; lanes cover 256 points/iter via
// float4. Per bin: 4 shared v_cmp, cndmask->t feeds both sum (v_add) and max (v_max3).
__global__ __launch_bounds__(256) void k2_feat(
    const float* __restrict__ features, const int* __restrict__ labels,
    float* __restrict__ sumf, float* __restrict__ maxf)
{
    const int tid  = threadIdx.x;
    const int lane = tid & 63;
    const int wid  = blockIdx.x*4 + (tid >> 6);   // 0..4095
    const int b    = wid >> 6;
    const int cp   = wid & 63;                    // channels cp and cp+64

    const float4* f0 = (const float4*)(features + ((size_t)b*CC + cp)*NN);
    const float4* f1 = f0 + (size_t)64*NN/4;
    const int4*   lr = (const int4*)(labels + (size_t)b*NN);

    float s0[KK], s1[KK], m0[KK], m1[KK];
    #pragma unroll
    for (int k = 0; k < KK; ++k) { s0[k]=0.f; s1[k]=0.f; m0[k]=0.f; m1[k]=0.f; }

    for (int it = 0; it < NN/256; ++it) {   // 64 iterations
        int idx = it*64 + lane;
        float4 a = f0[idx];
        float4 c = f1[idx];
        int4   l = lr[idx];
        #pragma unroll
        for (int k = 0; k < KK; ++k) {
            bool e0 = (l.x == k), e1 = (l.y == k), e2 = (l.z == k), e3 = (l.w == k);
            float t0 = e0 ? a.x : 0.f, t1 = e1 ? a.y : 0.f;
            float t2 = e2 ? a.z : 0.f, t3 = e3 ? a.w : 0.f;
            s0[k] += (t0 + t1) + (t2 + t3);
            m0[k] = fmaxf(fmaxf(m0[k], t0), t1);   // v_max3
            m0[k] = fmaxf(fmaxf(m0[k], t2), t3);
            float u0 = e0 ? c.x : 0.f, u1 = e1 ? c.y : 0.f;
            float u2 = e2 ? c.z : 0.f, u3 = e3 ? c.w : 0.f;
            s1[k] += (u0 + u1) + (u2 + u3);
            m1[k] = fmaxf(fmaxf(m1[k], u0), u1);
            m1[k] = fmaxf(fmaxf(m1[k], u2), u3);
        }
    }

    // wave butterfly reduction (all indices constant after unroll)
    #pragma unroll
    for (int k = 0; k < KK; ++k) {
        #pragma unroll
        for (int off = 32; off; off >>= 1) {
            s0[k] += __shfl_xor(s0[k], off, 64);
            s1[k] += __shfl_xor(s1[k], off, 64);
            m0[k] = fmaxf(m0[k], __shfl_xor(m0[k], off, 64));
            m1[k] = fmaxf(m1[k], __shfl_xor(m1[k], off, 64));
        }
    }

    if (lane == 0) {
        float* sp = sumf + (size_t)b*KK*CC + cp;
        float* mp = maxf + (size_t)b*KK*CC + cp;
        #pragma unroll
        for (int k = 0; k < KK; ++k) {
            sp[k*CC]      = s0[k];
            sp[k*CC + 64] = s1[k];
            mp[k*CC]      = m0[k];
            mp[k*CC + 64] = m1[k];
        }
    }
}

// ---------------- k3: fold partials + epilogue --------------------------------------
__global__ __launch_bounds__(128) void k3_final(
    const float* __restrict__ pcnt, const float* __restrict__ psxyz,
    const float* __restrict__ sumf, const float* __restrict__ maxf,
    float* __restrict__ out)
{
    const int bk = blockIdx.x;       // b*KK + k
    const int b  = bk / KK, k = bk % KK;
    const int c  = threadIdx.x;      // 0..127

    float cn = 0.f;
    #pragma unroll
    for (int ch = 0; ch < NCHUNK; ++ch) cn += pcnt[(b*NCHUNK + ch)*KK + k];
    float inv = 1.0f / fmaxf(cn, 1.0f);

    float* orow = out + (size_t)bk * OUTW;
    if (c < 3) {
        float s = 0.f;
        #pragma unroll
        for (int ch = 0; ch < NCHUNK; ++ch) s += psxyz[((b*NCHUNK + ch)*KK + k)*3 + c];
        orow[c] = s * inv;
    }
    float s    = sumf[(size_t)bk*CC + c];
    float mean = s * inv;
    orow[3 + c] = mean;
    float m    = maxf[(size_t)bk*CC + c];              // = max(0, seg_max)
    orow[3 + CC + c] = (cn > 0.f) ? fmaxf(m - mean, 0.f) : 0.f;
}

extern "C" void kernel_launch(void* const* d_in, const int* in_sizes, int n_in,
                              void* d_out, int out_size, void* d_ws, size_t ws_size,
                              hipStream_t stream) {
    const float* xyz      = (const float*)d_in[0];
    const float* features = (const float*)d_in[1];
    const int*   labels   = (const int*)d_in[2];
    float* out = (float*)d_out;

    char* ws = (char*)d_ws;
    const size_t SZ_SUMF = (size_t)BB*KK*CC*4;        // 786432 B
    const size_t SZ_PCNT = (size_t)BB*NCHUNK*KK*4;    // 98304 B
    float* sumf  = (float*)ws;
    float* maxf  = (float*)(ws + SZ_SUMF);
    float* pcnt  = (float*)(ws + 2*SZ_SUMF);
    float* psxyz = (float*)(ws + 2*SZ_SUMF + SZ_PCNT);

    k1_cnt_xyz<<<BB*NCHUNK, 256, 0, stream>>>(xyz, labels, pcnt, psxyz);
    k2_feat<<<BB*CC/2/4, 256, 0, stream>>>(features, labels, sumf, maxf);
    k3_final<<<BB*KK, 128, 0, stream>>>(pcnt, psxyz, sumf, maxf, out);
}